// Round 2
// baseline (308.537 us; speedup 1.0000x reference)
//
#include <hip/hip_runtime.h>
#include <hip/hip_bf16.h>
#include <cstdint>

// Problem constants
#define DM   1024        // d_model
#define NH   16          // heads
#define DK   64          // head dim
#define BB   4           // batch
#define SS   2048        // seq
#define MTOT (BB * SS)   // 8192 tokens
#define PAD  68          // attn LDS row stride (u16): 136B = 2-bank skew -> conflict-free frags

typedef short short8 __attribute__((ext_vector_type(8)));
typedef float f32x4  __attribute__((ext_vector_type(4)));
using u16 = unsigned short;

// bf16 <-> f32 (RNE, finite values only)
__device__ inline u16 f2b(float f) {
    union { float f; unsigned int u; } v; v.f = f;
    unsigned int u = v.u;
    u += 0x7fffu + ((u >> 16) & 1u);
    return (u16)(u >> 16);
}
// truncating pack (1 VALU): P in [0,128], downward bias <= 2^-8 rel — fine
__device__ inline u16 f2b_trunc(float f) {
    union { float f; unsigned int u; } v; v.f = f;
    return (u16)(v.u >> 16);
}
__device__ inline float b2f(u16 s) {
    union { unsigned int u; float f; } v; v.u = ((unsigned int)s) << 16;
    return v.f;
}

// async global->LDS, 16B per lane. LDS dest = wave-uniform base + lane*16.
__device__ inline void load_lds16(const u16* g, u16* l) {
    __builtin_amdgcn_global_load_lds(
        (const __attribute__((address_space(1))) unsigned int*)g,
        (__attribute__((address_space(3))) unsigned int*)l, 16, 0, 0);
}

// raw barrier (builtin = the verified m201 construct): no vmcnt(0) drain,
// unlike __syncthreads(). Counted vmcnt waits via asm (no builtin exists).
#define BARRIER()  __builtin_amdgcn_s_barrier()
#define WAITVM4()  asm volatile("s_waitcnt vmcnt(4)" ::: "memory")
#define WAITVM0()  asm volatile("s_waitcnt vmcnt(0)" ::: "memory")

// originals + converted-buffer pointers, passed by value to kernels
struct CvtPtrs {
    const void *x, *Wq, *Wk, *Wv, *Wo, *bq, *bk, *bv, *bo;
    u16 *xb, *Wqb, *Wkb, *Wvb, *Wob, *bqb, *bkb, *bvb, *bob;
};

// ---------------------------------------------------------------------------
// Fused dtype-detect + conversion (unchanged).
// ---------------------------------------------------------------------------
__global__ void convert_all(CvtPtrs p, int* __restrict__ flag)
{
    __shared__ int cnt;
    if (threadIdx.x == 0) cnt = 0;
    __syncthreads();
    int c = 0;
    for (int i = threadIdx.x; i < 512; i += 256) {
        const int e = (((const u16*)p.x)[i] >> 7) & 0xFF;
        if (e >= 100 && e <= 140) c++;
    }
    atomicAdd(&cnt, c);
    __syncthreads();
    const int isbf = (cnt >= 420) ? 1 : 0;
    if (blockIdx.x == 0 && threadIdx.x == 0) *flag = isbf;
    if (isbf) return;   // already bf16 — nothing to convert

    const size_t E  = (size_t)MTOT * DM;   // 2^23
    const size_t W1 = (size_t)DM * DM;     // 2^20
    const size_t i = ((size_t)blockIdx.x * blockDim.x + threadIdx.x) * 8;
    const float* s; u16* d; size_t off;
    if (i < E) {
        s = (const float*)p.x; d = p.xb; off = i;
    } else {
        size_t j = i - E;
        if (j < (W1 << 2)) {
            const int w = (int)(j >> 20); off = j & (W1 - 1);
            const float* ss[4] = {(const float*)p.Wq, (const float*)p.Wk,
                                  (const float*)p.Wv, (const float*)p.Wo};
            u16* dd[4] = {p.Wqb, p.Wkb, p.Wvb, p.Wob};
            s = ss[w]; d = dd[w];
        } else {
            j -= (W1 << 2);
            if (j >= 4 * DM) return;
            const int w = (int)(j >> 10); off = j & (DM - 1);
            const float* ss[4] = {(const float*)p.bq, (const float*)p.bk,
                                  (const float*)p.bv, (const float*)p.bo};
            u16* dd[4] = {p.bqb, p.bkb, p.bvb, p.bob};
            s = ss[w]; d = dd[w];
        }
    }
    const float4 f0 = *(const float4*)(s + off);
    const float4 f1 = *(const float4*)(s + off + 4);
    u16 tmp[8] = {f2b(f0.x), f2b(f0.y), f2b(f0.z), f2b(f0.w),
                  f2b(f1.x), f2b(f1.y), f2b(f1.z), f2b(f1.w)};
    *(int4*)(d + off) = *(const int4*)tmp;
}

// ---------------------------------------------------------------------------
// 8-phase GEMM machinery (T2+T3+T4+T5, plain HIP).
// NT GEMM: C[m,n] = sum_k A[m,k]*B[n,k] + bias[n]. bf16 in, fp32 acc.
// BM x 256 tile, BK=64, 512 threads = 8 waves (2M x 4N), per-wave BM/2 x 64.
// LDS double-buffered; XOR-swizzled rows (16B chunk c of row r stored at
// c ^ (r&7)); staging via global_load_lds w=16 with pre-swizzled global addr.
//
// Phase schedule per K-tile t (2 raw barriers per phase, no vmcnt(0) drain):
//   P1: ds_read A-lo + B-lo frags | stage A-half0(t+1) | bar | MFMA Qlo,lo | bar
//   P2: ds_read B-hi frags        | stage A-half1(t+1) | bar | MFMA Qlo,hi | bar
//   P3: ds_read A-hi frags        | stage B-half0(t+2) | bar | MFMA Qhi,hi | bar
//   P4:                           | stage B-half1(t+2) | bar | MFMA Qhi,lo |
//       s_waitcnt vmcnt(N) | bar
// Region safety: B-LDS reads are register-resident before the end-P2 barrier
// -> staging t+2's B into the same buffer at P3/P4 is WAR-safe. A(t+1) goes
// to the other buffer, whose A reads ended at (t-1).P3.
// vmcnt(N): per tile a wave issues A(t+1) at P1/P2 and B(t+2) at P3/P4.
// Steady state (t<14): newest 4 at the P4 wait = t+2's B halves; everything
// tile t+1 needs is older -> N=4. TAIL (t>=14): nothing staged at P3/P4, so
// the newest loads are A(t+1) itself -> must drain with N=0 (fixes the race
// where tile 15 read A before its global_load_lds landed).
// Prologue: stage tile0 (A0,A1,B0,B1) + tile1 (B0,B1), vmcnt(4), barrier.
// ---------------------------------------------------------------------------
template<int ROWS>   // rows per half: 128 (BM=256) or 64 (BM=128)
__device__ __forceinline__
void stage_half(const u16* __restrict__ g, int grow0, int k0,
                u16 (*lds)[64], int r0, int wave, int lane)
{
    const int lrow  = lane >> 3;            // 0..7 within the wave's 8 rows
    const int chunk = (lane & 7) ^ lrow;    // pre-swizzled global 16B chunk
#pragma unroll
    for (int i2 = 0; i2 < ROWS / 64; i2++) {
        const u16* src = g + (size_t)(grow0 + 64*i2 + 8*wave + lrow) * DM
                           + k0 + chunk * 8;
        load_lds16(src, &lds[r0 + 64*i2 + 8*wave][0]);   // wave-uniform base
    }
}

__device__ __forceinline__
short8 lds_frag(u16 (*t)[64], int row, int kc)
{
    return *(const short8*)(&t[row][(kc ^ (row & 7)) * 8]);
}

template<int BM>
__device__ __forceinline__
void gemm_body8p(const u16* __restrict__ A, const u16* __restrict__ Bw,
                 const u16* __restrict__ bias, void* __restrict__ out,
                 int mode, float scale, int isbf, int m0, int n0,
                 u16 (*As)[64], u16 (*Bs)[64])
{
    constexpr int BMW = BM / 2;    // wave rows
    constexpr int MQ  = BM / 64;   // m-frags per phase (quadrant)
    const int tid  = threadIdx.x;
    const int wave = tid >> 6;
    const int lane = tid & 63;
    const int wm = wave >> 2;      // 0..1
    const int wn = wave & 3;       // 0..3
    const int lm = lane & 15, quad = lane >> 4, rq = quad * 4;
    const int ar0 = wm * BMW;
    const int br0 = wn * 64;

    const u16* Ag = A  + (size_t)m0 * DM;
    const u16* Bg = Bw + (size_t)n0 * DM;
    u16 (*As0)[64] = As;  u16 (*As1)[64] = As + BM;
    u16 (*Bs0)[64] = Bs;  u16 (*Bs1)[64] = Bs + 256;

    // ---- prologue: tile0 fully + tile1's B halves ----
    stage_half<BMW>(Ag, 0,   0,  As0, 0,   wave, lane);
    stage_half<BMW>(Ag, BMW, 0,  As0, BMW, wave, lane);
    stage_half<128>(Bg, 0,   0,  Bs0, 0,   wave, lane);
    stage_half<128>(Bg, 128, 0,  Bs0, 128, wave, lane);
    stage_half<128>(Bg, 0,   64, Bs1, 0,   wave, lane);
    stage_half<128>(Bg, 128, 64, Bs1, 128, wave, lane);
    WAITVM4();           // tile0's loads landed; tile1's 4 B-loads in flight
    BARRIER();

    f32x4 acc[2*MQ][4] = {};

#pragma unroll 2
    for (int t = 0; t < 16; ++t) {
        u16 (*Al)[64] = (t & 1) ? As1 : As0;
        u16 (*Bl)[64] = (t & 1) ? Bs1 : Bs0;
        u16 (*An)[64] = (t & 1) ? As0 : As1;
        const int kn1 = (t + 1) * 64, kn2 = (t + 2) * 64;

        short8 af[MQ][2], bA[2][2], bB[2][2];

        // ---------------- P1: (m-lo, n-lo) ----------------
#pragma unroll
        for (int i = 0; i < MQ; i++)
#pragma unroll
            for (int ks = 0; ks < 2; ks++)
                af[i][ks] = lds_frag(Al, ar0 + 16*i + lm, ks*4 + quad);
#pragma unroll
        for (int j = 0; j < 2; j++)
#pragma unroll
            for (int ks = 0; ks < 2; ks++)
                bA[j][ks] = lds_frag(Bl, br0 + 16*j + lm, ks*4 + quad);
        if (t + 1 < 16) stage_half<BMW>(Ag, 0, kn1, An, 0, wave, lane);
        BARRIER();
        __builtin_amdgcn_s_setprio(1);
#pragma unroll
        for (int i = 0; i < MQ; i++)
#pragma unroll
            for (int j = 0; j < 2; j++)
#pragma unroll
                for (int ks = 0; ks < 2; ks++)
                    acc[i][j] = __builtin_amdgcn_mfma_f32_16x16x32_bf16(
                        af[i][ks], bA[j][ks], acc[i][j], 0, 0, 0);
        __builtin_amdgcn_s_setprio(0);
        BARRIER();

        // ---------------- P2: (m-lo, n-hi) ----------------
#pragma unroll
        for (int j = 0; j < 2; j++)
#pragma unroll
            for (int ks = 0; ks < 2; ks++)
                bB[j][ks] = lds_frag(Bl, br0 + 32 + 16*j + lm, ks*4 + quad);
        if (t + 1 < 16) stage_half<BMW>(Ag, BMW, kn1, An, BMW, wave, lane);
        BARRIER();
        __builtin_amdgcn_s_setprio(1);
#pragma unroll
        for (int i = 0; i < MQ; i++)
#pragma unroll
            for (int j = 0; j < 2; j++)
#pragma unroll
                for (int ks = 0; ks < 2; ks++)
                    acc[i][2+j] = __builtin_amdgcn_mfma_f32_16x16x32_bf16(
                        af[i][ks], bB[j][ks], acc[i][2+j], 0, 0, 0);
        __builtin_amdgcn_s_setprio(0);
        BARRIER();

        // ---------------- P3: (m-hi, n-hi) ----------------
#pragma unroll
        for (int i = 0; i < MQ; i++)
#pragma unroll
            for (int ks = 0; ks < 2; ks++)
                af[i][ks] = lds_frag(Al, ar0 + MQ*16 + 16*i + lm, ks*4 + quad);
        if (t + 2 < 16) stage_half<128>(Bg, 0, kn2, Bl, 0, wave, lane);
        BARRIER();
        __builtin_amdgcn_s_setprio(1);
#pragma unroll
        for (int i = 0; i < MQ; i++)
#pragma unroll
            for (int j = 0; j < 2; j++)
#pragma unroll
                for (int ks = 0; ks < 2; ks++)
                    acc[MQ+i][2+j] = __builtin_amdgcn_mfma_f32_16x16x32_bf16(
                        af[i][ks], bB[j][ks], acc[MQ+i][2+j], 0, 0, 0);
        __builtin_amdgcn_s_setprio(0);
        BARRIER();

        // ---------------- P4: (m-hi, n-lo) ----------------
        if (t + 2 < 16) stage_half<128>(Bg, 128, kn2, Bl, 128, wave, lane);
        BARRIER();
        __builtin_amdgcn_s_setprio(1);
#pragma unroll
        for (int i = 0; i < MQ; i++)
#pragma unroll
            for (int j = 0; j < 2; j++)
#pragma unroll
                for (int ks = 0; ks < 2; ks++)
                    acc[MQ+i][j] = __builtin_amdgcn_mfma_f32_16x16x32_bf16(
                        af[i][ks], bA[j][ks], acc[MQ+i][j], 0, 0, 0);
        __builtin_amdgcn_s_setprio(0);
        // steady state: newest 4 = t+2's B halves, t+1 fully landed.
        // tail (t>=14): nothing staged at P3/P4 -> newest = A(t+1): drain.
        if (t < 14) WAITVM4(); else WAITVM0();
        BARRIER();
    }

    // ---- epilogue ----
#pragma unroll
    for (int j = 0; j < 4; j++) {
        const int col = n0 + wn*64 + 16*j + lm;
        const float bvl = b2f(bias[col]);
        const int h = col >> 6, d = col & 63;
#pragma unroll
        for (int i = 0; i < 2*MQ; i++) {
            if (mode == 2) {
                const int row0 = m0 + wm*BMW + 16*i + rq;
                const int b = row0 >> 11, s = row0 & 2047;
                u16 tmp[4];
#pragma unroll
                for (int r = 0; r < 4; r++)
                    tmp[r] = f2b((acc[i][j][r] + bvl) * scale);
                const size_t idx = (((size_t)(b*NH + h) * DK) + d) * SS + s;
                *(uint2*)(&((u16*)out)[idx]) = *(const uint2*)tmp;
            } else {
#pragma unroll
                for (int r = 0; r < 4; r++) {
                    const int row = m0 + wm*BMW + 16*i + rq + r;
                    const float v = (acc[i][j][r] + bvl) * scale;
                    if (mode == 0) {
                        const size_t idx = (size_t)row * DM + col;
                        if (isbf) ((u16*)out)[idx] = f2b(v);
                        else      ((float*)out)[idx] = v;
                    } else {
                        const int b = row >> 11, s = row & 2047;
                        const size_t idx = (((size_t)(b*NH + h) * SS) + s) * DK + d;
                        ((u16*)out)[idx] = f2b(v);
                    }
                }
            }
        }
    }
}

// Fused QKV projection: grid 384 (= 8 XCD x 4m x 12n, bijective since 384%8=0).
// n-major within an XCD: 4 consecutive blocks reuse one 0.5MB B-panel; the
// XCD's 4 A-strips (2MB) stay resident in its private L2.
__global__ __launch_bounds__(512, 2)
void gemm_qkv(CvtPtrs p, u16* __restrict__ Qb, u16* __restrict__ Kb,
              u16* __restrict__ Vb, float qscale, const int* __restrict__ flag)
{
    __shared__ __align__(16) u16 As[512][64];   // 2 x 256 x 64 bf16 = 64KB
    __shared__ __align__(16) u16 Bs[512][64];   // 64KB -> 128KB total
    const int id  = blockIdx.x;
    const int xcd = id & 7;
    const int jb  = id >> 3;               // 0..47
    const int m0  = (xcd*4 + (jb & 3)) * 256;
    const int nti = jb >> 2;               // 0..11
    const int z   = nti >> 2;              // 0..2
    const int n0  = (nti & 3) * 256;
    const int isbf = *flag;
    const u16* A = isbf ? (const u16*)p.x : p.xb;
    const u16 *Bw, *bias; u16* out; int mode; float sc;
    if (z == 0)      { Bw = isbf ? (const u16*)p.Wq : p.Wqb; bias = isbf ? (const u16*)p.bq : p.bqb; out = Qb; mode = 1; sc = qscale; }
    else if (z == 1) { Bw = isbf ? (const u16*)p.Wk : p.Wkb; bias = isbf ? (const u16*)p.bk : p.bkb; out = Kb; mode = 1; sc = 1.0f; }
    else             { Bw = isbf ? (const u16*)p.Wv : p.Wvb; bias = isbf ? (const u16*)p.bv : p.bvb; out = Vb; mode = 2; sc = 1.0f; }
    gemm_body8p<256>(A, Bw, bias, out, mode, sc, 1, m0, n0, As, Bs);
}

// Output projection: BM=128 -> grid 256 = exactly one full dispatch round
// (BM=256 would give 128 blocks = half the GPU idle). 96KB LDS.
__global__ __launch_bounds__(512, 2)
void gemm_out(const u16* __restrict__ Ab, CvtPtrs p, void* __restrict__ out,
              const int* __restrict__ flag)
{
    __shared__ __align__(16) u16 As[256][64];   // 2 x 128 x 64 = 32KB
    __shared__ __align__(16) u16 Bs[512][64];   // 64KB -> 96KB total
    const int id  = blockIdx.x;
    const int xcd = id & 7;
    const int jb  = id >> 3;               // 0..31
    const int m0  = (xcd*8 + (jb & 7)) * 128;
    const int n0  = (jb >> 3) * 256;
    const int isbf = *flag;
    const u16* Bw   = isbf ? (const u16*)p.Wo : p.Wob;
    const u16* bias = isbf ? (const u16*)p.bo : p.bob;
    gemm_body8p<128>(Ab, Bw, bias, out, 0, 1.0f, isbf, m0, n0, As, Bs);
}

// ---------------------------------------------------------------------------
// Streaming-softmax causal attention (unchanged this round).
// ---------------------------------------------------------------------------
__global__ __launch_bounds__(256)
void attn_causal(const u16* __restrict__ Q, const u16* __restrict__ K,
                 const u16* __restrict__ VT, u16* __restrict__ O)
{
    __shared__ __align__(16) u16 Ks[2][64][PAD];
    __shared__ __align__(16) u16 Vs[2][64][PAD];   // V^T tiles: [d][k]
    __shared__ __align__(16) u16 Ps[128][PAD];

    const int tid  = threadIdx.x;
    const int wave = tid >> 6;
    const int lane = tid & 63;
    const int qx = blockIdx.x;             // 0..7
    const int h = blockIdx.y, b = blockIdx.z;
    const int bh = b * NH + h;

    const u16* Kg = K  + (size_t)bh * SS * DK;
    const u16* Vg = VT + (size_t)bh * DK * SS;

    const int srow = tid >> 3;        // 0..31 (two passes: +0, +32)
    const int scol = (tid & 7) * 8;   // 0..56
    const int lm = lane & 15, quad = lane >> 4, kq = quad * 8, rq = quad * 4;

#pragma unroll
    for (int seg = 0; seg < 2; seg++) {
        const int qt = seg ? (15 - qx) : qx;
        const int q0 = qt * 128;
        const int nt = 2 * (qt + 1);
        const u16* Qg = Q + ((size_t)bh * SS + q0) * DK;

        // Q fragments straight from global (A-frag = 16B contiguous per lane)
        short8 qa[2][2];
#pragma unroll
        for (int mi = 0; mi < 2; mi++)
#pragma unroll
            for (int ks = 0; ks < 2; ks++)
                qa[mi][ks] = *(const short8*)(&Qg[(size_t)(32*wave + 16*mi + lm) * DK + ks*32 + kq]);

        // tile 0: regs -> buf0
        int4 kv0 = *(const int4*)(&Kg[(size_t)srow * DK + scol]);
        int4 kv1 = *(const int4*)(&Kg[(size_t)(srow + 32) * DK + scol]);
        int4 vv0 = *(const int4*)(&Vg[(size_t)srow * SS + scol]);
        int4 vv1 = *(const int4*)(&Vg[(size_t)(srow + 32) * SS + scol]);
        *(int4*)(&Ks[0][srow][scol])      = kv0;
        *(int4*)(&Ks[0][srow + 32][scol]) = kv1;
        *(int4*)(&Vs[0][srow][scol])      = vv0;
        *(int4*)(&Vs[0][srow + 32][scol]) = vv1;
        __syncthreads();   // tile0 visible (and prev segment's reads done)

        // prefetch tile 1 (nt >= 2 always)
        kv0 = *(const int4*)(&Kg[(size_t)(64 + srow) * DK + scol]);
        kv1 = *(const int4*)(&Kg[(size_t)(64 + srow + 32) * DK + scol]);
        vv0 = *(const int4*)(&Vg[(size_t)srow * SS + 64 + scol]);
        vv1 = *(const int4*)(&Vg[(size_t)(srow + 32) * SS + 64 + scol]);

        f32x4 o[2][4] = {};
        float lacc[2][4] = {};

        for (int t = 0; t < nt; t++) {
            const int buf = t & 1;
            const int k0 = 64 * t;

            // S = Q K^T  (2 m-frags share each B-frag read)
            f32x4 sc[2][4] = {};
#pragma unroll
            for (int ks = 0; ks < 2; ks++)
#pragma unroll
                for (int j = 0; j < 4; j++) {
                    const short8 bfr = *(const short8*)(&Ks[buf][16*j + lm][ks*32 + kq]);
                    sc[0][j] = __builtin_amdgcn_mfma_f32_16x16x32_bf16(qa[0][ks], bfr, sc[0][j], 0, 0, 0);
                    sc[1][j] = __builtin_amdgcn_mfma_f32_16x16x32_bf16(qa[1][ks], bfr, sc[1][j], 0, 0, 0);
                }

            if (k0 + 63 > q0 + 32*wave) {   // wave-uniform: mask can affect this wave
#pragma unroll
                for (int mi = 0; mi < 2; mi++)
#pragma unroll
                    for (int j = 0; j < 4; j++)
#pragma unroll
                        for (int r = 0; r < 4; r++)
                            if (k0 + 16*j + lm > q0 + 32*wave + 16*mi + rq + r)
                                sc[mi][j][r] = -1e30f;
            }

            // p = exp2(s); per-lane partial row sums; stash P (trunc bf16)
#pragma unroll
            for (int mi = 0; mi < 2; mi++)
#pragma unroll
                for (int j = 0; j < 4; j++)
#pragma unroll
                    for (int r = 0; r < 4; r++) {
                        const float pv = __builtin_amdgcn_exp2f(sc[mi][j][r]);
                        lacc[mi][r] += pv;
                        Ps[32*wave + 16*mi + rq + r][16*j + lm] = f2b_trunc(pv);
                    }

            // O += P * V   (Ps rows wave-private; same-wave LDS ordering)
#pragma unroll
            for (int ks = 0; ks < 2; ks++) {
                const short8 pa0 = *(const short8*)(&Ps[32*wave + lm][ks*32 + kq]);
                const short8 pa1 = *(const short8*)(&Ps[32*wave + 16 + lm][ks*32 + kq]);
#pragma unroll
                for (int j = 0; j < 4; j++) {
                    const short8 vfr = *(const short8*)(&Vs[buf][16*j + lm][ks*32 + kq]);
                    o[0][j] = __builtin_amdgcn_mfma_f32_16x16x32_bf16(pa0, vfr, o[0][j], 0, 0, 0);
                    o[1][j] = __builtin_amdgcn_mfma_f32_16x16x32_bf16(pa1, vfr, o[1][j], 0, 0, 0);
                }
            }

            // stage tile t+1 into the other buffer; then prefetch tile t+2
            if (t + 1 < nt) {
                const int nb = buf ^ 1;
                *(int4*)(&Ks[nb][srow][scol])      = kv0;
                *(int4*)(&Ks[nb][srow + 32][scol]) = kv1;
                *(int4*)(&Vs[nb][srow][scol])      = vv0;
                *(int4*)(&Vs[nb][srow + 32][scol]) = vv1;
                if (t + 2 < nt) {
                    const int kn = 64 * (t + 2);
                    kv0 = *(const int4*)(&Kg[(size_t)(kn + srow) * DK + scol]);
                    kv1 = *(const int4*)(&Kg[(size_t)(kn + srow + 32) * DK + scol]);
                    vv0 = *(const int4*)(&Vg[(size_t)srow * SS + kn + scol]);
                    vv1 = *(const int4*)(&Vg[(size_t)(srow + 32) * SS + kn + scol]);
                }
            }
            __syncthreads();   // stores(t+1) visible; reads(t) done before overwrite
        }

        // segment epilogue: row-sum reduce + normalize + write [B,S,DM]
#pragma unroll
        for (int mi = 0; mi < 2; mi++)
#pragma unroll
            for (int r = 0; r < 4; r++) {
                float v = lacc[mi][r];
#pragma unroll
                for (int off = 1; off < 16; off <<= 1)
                    v += __shfl_xor(v, off, 64);
                const float inv = 1.f / v;
                const size_t rowg = (size_t)b * SS + q0 + 32*wave + 16*mi + rq + r;
#pragma unroll
                for (int j = 0; j < 4; j++)
                    O[rowg * DM + h*DK + 16*j + lm] = f2b(o[mi][j][r] * inv);
            }
    }
}

extern "C" void kernel_launch(void* const* d_in, const int* in_sizes, int n_in,
                              void* d_out, int out_size, void* d_ws, size_t ws_size,
                              hipStream_t stream)
{
    (void)in_sizes; (void)n_in; (void)out_size; (void)ws_size;

    int* flag = (int*)d_ws;
    u16* ws = (u16*)((char*)d_ws + 16);

    const size_t E  = (size_t)MTOT * DM;
    const size_t W1 = (size_t)DM * DM;
    u16* xb  = ws;                 // [B,S,DM] bf16; reused as Ab later
    u16* Wqb = ws + E;
    u16* Wkb = Wqb + W1;
    u16* Wvb = Wkb + W1;
    u16* Wob = Wvb + W1;
    u16* bqb = Wob + W1;
    u16* bkb = bqb + DM;
    u16* bvb = bkb + DM;
    u16* bob = bvb + DM;
    u16* Qb  = bob + DM;           // [B,H,S,dk] (pre-scaled)
    u16* Kb  = Qb + E;             // [B,H,S,dk]
    u16* Vb  = Kb + E;             // [B,H,dk,S] (V^T)
    u16* Ab  = xb;                 // attention out [B,S,DM]; x dead by then

    CvtPtrs p;
    p.x = d_in[0];
    // d_in[1] = mask (int32) — causal, handled analytically
    p.Wq = d_in[2]; p.bq = d_in[3];
    p.Wk = d_in[4]; p.bk = d_in[5];
    p.Wv = d_in[6]; p.bv = d_in[7];
    p.Wo = d_in[8]; p.bo = d_in[9];
    p.xb = xb;
    p.Wqb = Wqb; p.Wkb = Wkb; p.Wvb = Wvb; p.Wob = Wob;
    p.bqb = bqb; p.bkb = bkb; p.bvb = bvb; p.bob = bob;

    const int cvt_blocks = (int)((E + 4*W1 + 4*DM) / 2048);   // 6146
    convert_all<<<cvt_blocks, 256, 0, stream>>>(p, flag);

    const float qscale = 0.18033688011112042f;  // (1/sqrt(64)) * log2(e)

    gemm_qkv<<<384, 512, 0, stream>>>(p, Qb, Kb, Vb, qscale, flag);
    attn_causal<<<dim3(SS/256, NH, BB), 256, 0, stream>>>(Qb, Kb, Vb, Ab);
    gemm_out<<<256, 512, 0, stream>>>(Ab, p, d_out, flag);
}